// Round 1
// baseline (512.074 us; speedup 1.0000x reference)
//
#include <hip/hip_runtime.h>
#include <hip/hip_bf16.h>
#include <math.h>

typedef __bf16 bf16;
typedef __attribute__((ext_vector_type(8))) __bf16 bf16x8;
typedef __attribute__((ext_vector_type(4))) __bf16 bf16x4;
typedef __attribute__((ext_vector_type(4))) float f32x4;

// Tile config: 128x128 block tile, BK=32, 256 threads (4 waves, each 64x64).
constexpr int BM = 128, BN = 128, BK = 32;
constexpr int LDK = BK + 24;  // 56 elems = 112 B row stride: 16B-aligned, 2-way bank aliasing (free)

enum { EPI_PLAIN = 0, EPI_GELU = 1, EPI_RES = 2, EPI_GATE = 3 };

// C = A[M,K] @ B[N,K]^T (+ epilogue). A: fp32 or bf16 (converted during LDS staging).
// B: bf16. All dims divisible by tile sizes (M=16384, N in {768,1536}, K in {768,1536}).
template <typename AT, typename CT, int EPI>
__global__ __launch_bounds__(256, 2) void gemm_bt(
    const AT* __restrict__ A, const bf16* __restrict__ B, CT* __restrict__ C,
    const float* __restrict__ bias, const float* __restrict__ resid,
    const float* __restrict__ sup, const float* __restrict__ wsg,
    const float* __restrict__ bsg, int M, int N, int K) {
  __shared__ bf16 As[BM][LDK];
  __shared__ bf16 Bs[BN][LDK];

  const int tid = threadIdx.x;
  const int bm = blockIdx.x, bn = blockIdx.y;
  const int lane = tid & 63;
  const int w = tid >> 6;
  const int wm = (w >> 1) * 64, wn = (w & 1) * 64;
  const int quad = lane >> 4, l16 = lane & 15;

  f32x4 acc[4][4];
#pragma unroll
  for (int i = 0; i < 4; i++)
#pragma unroll
    for (int j = 0; j < 4; j++) acc[i][j] = f32x4{0.f, 0.f, 0.f, 0.f};

  const AT* Ab = A + (size_t)(bm * BM) * K;
  const bf16* Bb = B + (size_t)(bn * BN) * K;

  for (int kk = 0; kk < K; kk += BK) {
    // ---- stage A tile (128 x 32) ----
    if constexpr (sizeof(AT) == 4) {
      // fp32 -> bf16 convert. 1024 float4s, 4 per thread.
#pragma unroll
      for (int it = 0; it < 4; ++it) {
        int id = it * 256 + tid;
        int row = id >> 3, k4 = id & 7;
        f32x4 v = *(const f32x4*)((const float*)Ab + (size_t)row * K + kk + k4 * 4);
        bf16x4 b;
        b[0] = (bf16)v[0]; b[1] = (bf16)v[1]; b[2] = (bf16)v[2]; b[3] = (bf16)v[3];
        *(bf16x4*)&As[row][k4 * 4] = b;
      }
    } else {
      // bf16 direct. 512 bf16x8s, 2 per thread.
#pragma unroll
      for (int it = 0; it < 2; ++it) {
        int id = it * 256 + tid;
        int row = id >> 2, k8 = id & 3;
        bf16x8 v = *(const bf16x8*)((const bf16*)Ab + (size_t)row * K + kk + k8 * 8);
        *(bf16x8*)&As[row][k8 * 8] = v;
      }
    }
    // ---- stage B tile (128 x 32) ----
#pragma unroll
    for (int it = 0; it < 2; ++it) {
      int id = it * 256 + tid;
      int row = id >> 2, k8 = id & 3;
      bf16x8 v = *(const bf16x8*)(Bb + (size_t)row * K + kk + k8 * 8);
      *(bf16x8*)&Bs[row][k8 * 8] = v;
    }
    __syncthreads();

    // ---- MFMA: each wave 4x4 tiles of 16x16x32 ----
    bf16x8 af[4], bfr[4];
#pragma unroll
    for (int i = 0; i < 4; i++) af[i] = *(const bf16x8*)&As[wm + i * 16 + l16][quad * 8];
#pragma unroll
    for (int j = 0; j < 4; j++) bfr[j] = *(const bf16x8*)&Bs[wn + j * 16 + l16][quad * 8];
#pragma unroll
    for (int i = 0; i < 4; i++)
#pragma unroll
      for (int j = 0; j < 4; j++)
        acc[i][j] = __builtin_amdgcn_mfma_f32_16x16x32_bf16(af[i], bfr[j], acc[i][j], 0, 0, 0);
    __syncthreads();
  }

  // ---- epilogue: D row = quad*4+reg, col = lane&15 ----
#pragma unroll
  for (int i = 0; i < 4; i++) {
    int row0 = bm * BM + wm + i * 16 + quad * 4;
#pragma unroll
    for (int j = 0; j < 4; j++) {
      int col = bn * BN + wn + j * 16 + l16;
#pragma unroll
      for (int r = 0; r < 4; r++) {
        int row = row0 + r;
        size_t idx = (size_t)row * N + col;
        float v = acc[i][j][r];
        if constexpr (EPI == EPI_PLAIN) {
          C[idx] = (CT)v;
        } else if constexpr (EPI == EPI_GELU) {
          v += bias[col];
          float gl = 0.5f * v * (1.0f + erff(v * 0.70710678118654752f));
          C[idx] = (CT)gl;
        } else if constexpr (EPI == EPI_RES) {
          v += bias[col] + resid[idx];
          C[idx] = (CT)v;
        } else {  // EPI_GATE: sigmoid(v+b) * sigmoid(sup*wsg+bsg)
          v += bias[col];
          float g1 = 1.0f / (1.0f + expf(-v));
          float z = sup[row] * wsg[col] + bsg[col];
          float g2 = 1.0f / (1.0f + expf(-z));
          C[idx] = (CT)(g1 * g2);
        }
      }
    }
  }
}

// s_t = (1-g_t)*s_{t-1} + g_t*xt_t over t, per (n,c). One thread per channel.
__global__ __launch_bounds__(256) void scan_kernel(const float* __restrict__ g,
                                                   const float* __restrict__ xt,
                                                   float* __restrict__ s, int T, int C) {
  int c = blockIdx.x * 256 + threadIdx.x;
  int n = blockIdx.y;
  size_t base = (size_t)n * T * C + c;
  float sv = 0.f;
  for (int t = 0; t < T; ++t) {
    size_t idx = base + (size_t)t * C;
    float gv = g[idx], xv = xt[idx];
    sv = (1.0f - gv) * sv + gv * xv;
    s[idx] = sv;
  }
}

__global__ __launch_bounds__(256) void cvt_kernel(const float* __restrict__ in,
                                                  bf16* __restrict__ out, int n) {
  int i = blockIdx.x * 256 + threadIdx.x;
  if (i < n) out[i] = (bf16)in[i];
}

extern "C" void kernel_launch(void* const* d_in, const int* in_sizes, int n_in,
                              void* d_out, int out_size, void* d_ws, size_t ws_size,
                              hipStream_t stream) {
  const float* x_seq = (const float*)d_in[0];
  const float* sup = (const float*)d_in[1];
  const float* W_in = (const float*)d_in[2];
  const float* W_out = (const float*)d_in[3];
  const float* W_bg = (const float*)d_in[4];
  const float* b_bg = (const float*)d_in[5];
  const float* W_sg = (const float*)d_in[6];
  const float* b_sg = (const float*)d_in[7];
  const float* W_f1 = (const float*)d_in[8];
  const float* b_f1 = (const float*)d_in[9];
  const float* W_f2 = (const float*)d_in[10];
  const float* b_f2 = (const float*)d_in[11];

  const int Nb = 32, T = 512, C = 768, H = 1536;
  const int M = Nb * T;  // 16384

  char* ws = (char*)d_ws;
  size_t off = 0;
  auto alloc = [&](size_t bytes) {
    void* p = ws + off;
    off += (bytes + 255) & ~(size_t)255;
    return p;
  };
  bf16* Win_bf = (bf16*)alloc((size_t)C * C * 2);
  bf16* Wf1_bf = (bf16*)alloc((size_t)H * C * 2);
  bf16* Wf2_bf = (bf16*)alloc((size_t)C * H * 2);
  bf16* Wbg_bf = (bf16*)alloc((size_t)C * C * 2);
  bf16* Wout_bf = (bf16*)alloc((size_t)C * C * 2);
  float* x_f = (float*)alloc((size_t)M * C * 4);   // x; reused as s after G4
  bf16* h_bf = (bf16*)alloc((size_t)M * H * 2);
  float* xt_f = (float*)alloc((size_t)M * C * 4);
  float* g_f = (float*)alloc((size_t)M * C * 4);
  float* s_f = x_f;  // x dead after G3

  auto cvt = [&](const float* src, bf16* dst, int n) {
    cvt_kernel<<<(n + 255) / 256, 256, 0, stream>>>(src, dst, n);
  };
  cvt(W_in, Win_bf, C * C);
  cvt(W_f1, Wf1_bf, H * C);
  cvt(W_f2, Wf2_bf, C * H);
  cvt(W_bg, Wbg_bf, C * C);
  cvt(W_out, Wout_bf, C * C);

  dim3 blk(256);
  // G1: x = x_seq @ W_in^T
  gemm_bt<float, float, EPI_PLAIN><<<dim3(M / BM, C / BN), blk, 0, stream>>>(
      x_seq, Win_bf, x_f, nullptr, nullptr, nullptr, nullptr, nullptr, M, C, C);
  // G2: h = gelu(x @ W_f1^T + b_f1)  (bf16 out)
  gemm_bt<float, bf16, EPI_GELU><<<dim3(M / BM, H / BN), blk, 0, stream>>>(
      x_f, Wf1_bf, h_bf, b_f1, nullptr, nullptr, nullptr, nullptr, M, H, C);
  // G3: xt = x + h @ W_f2^T + b_f2
  gemm_bt<bf16, float, EPI_RES><<<dim3(M / BM, C / BN), blk, 0, stream>>>(
      h_bf, Wf2_bf, xt_f, b_f2, x_f, nullptr, nullptr, nullptr, M, C, H);
  // G4: g = sigmoid(xt @ W_bg^T + b_bg) * sigmoid(sup*W_sg + b_sg)
  gemm_bt<float, float, EPI_GATE><<<dim3(M / BM, C / BN), blk, 0, stream>>>(
      xt_f, Wbg_bf, g_f, b_bg, nullptr, sup, W_sg, b_sg, M, C, C);
  // scan: s_t = (1-g)*s_{t-1} + g*xt
  scan_kernel<<<dim3(C / 256, Nb), blk, 0, stream>>>(g_f, xt_f, s_f, T, C);
  // G6: out = s @ W_out^T
  gemm_bt<float, float, EPI_PLAIN><<<dim3(M / BM, C / BN), blk, 0, stream>>>(
      s_f, Wout_bf, (float*)d_out, nullptr, nullptr, nullptr, nullptr, nullptr, M, C, C);
}

// Round 2
// 393.161 us; speedup vs baseline: 1.3025x; 1.3025x over previous
//
#include <hip/hip_runtime.h>
#include <hip/hip_bf16.h>
#include <math.h>

typedef __bf16 bf16;
typedef __attribute__((ext_vector_type(8))) __bf16 bf16x8;
typedef __attribute__((ext_vector_type(4))) __bf16 bf16x4;
typedef __attribute__((ext_vector_type(4))) float f32x4;

// Tile config: 128x128 block tile, BK=32, 256 threads (4 waves, each 64x64).
constexpr int BM = 128, BN = 128, BK = 32;
constexpr int LDK = BK + 24;  // 56 elems = 112 B row stride: 16B-aligned, 2-way bank aliasing (free)

enum { EPI_PLAIN = 0, EPI_GELU = 1, EPI_RES = 2, EPI_GATE = 3 };

// C = A[M,K] @ B[N,K]^T (+ epilogue). A: fp32 or bf16 (converted during LDS staging).
// B: bf16. All dims divisible by tile sizes (M=16384, N in {768,1536}, K in {768,1536}).
template <typename AT, typename CT, int EPI>
__global__ __launch_bounds__(256, 2) void gemm_bt(
    const AT* __restrict__ A, const bf16* __restrict__ B, CT* __restrict__ C,
    const float* __restrict__ bias, const float* __restrict__ resid,
    const float* __restrict__ sup, const float* __restrict__ wsg,
    const float* __restrict__ bsg, int M, int N, int K) {
  __shared__ bf16 As[BM][LDK];
  __shared__ bf16 Bs[BN][LDK];

  const int tid = threadIdx.x;
  const int bm = blockIdx.x, bn = blockIdx.y;
  const int lane = tid & 63;
  const int w = tid >> 6;
  const int wm = (w >> 1) * 64, wn = (w & 1) * 64;
  const int quad = lane >> 4, l16 = lane & 15;

  f32x4 acc[4][4];
#pragma unroll
  for (int i = 0; i < 4; i++)
#pragma unroll
    for (int j = 0; j < 4; j++) acc[i][j] = f32x4{0.f, 0.f, 0.f, 0.f};

  const AT* Ab = A + (size_t)(bm * BM) * K;
  const bf16* Bb = B + (size_t)(bn * BN) * K;

  for (int kk = 0; kk < K; kk += BK) {
    // ---- stage A tile (128 x 32) ----
    if constexpr (sizeof(AT) == 4) {
      // fp32 -> bf16 convert. 1024 float4s, 4 per thread.
#pragma unroll
      for (int it = 0; it < 4; ++it) {
        int id = it * 256 + tid;
        int row = id >> 3, k4 = id & 7;
        f32x4 v = *(const f32x4*)((const float*)Ab + (size_t)row * K + kk + k4 * 4);
        bf16x4 b;
        b[0] = (bf16)v[0]; b[1] = (bf16)v[1]; b[2] = (bf16)v[2]; b[3] = (bf16)v[3];
        *(bf16x4*)&As[row][k4 * 4] = b;
      }
    } else {
      // bf16 direct. 512 bf16x8s, 2 per thread.
#pragma unroll
      for (int it = 0; it < 2; ++it) {
        int id = it * 256 + tid;
        int row = id >> 2, k8 = id & 3;
        bf16x8 v = *(const bf16x8*)((const bf16*)Ab + (size_t)row * K + kk + k8 * 8);
        *(bf16x8*)&As[row][k8 * 8] = v;
      }
    }
    // ---- stage B tile (128 x 32) ----
#pragma unroll
    for (int it = 0; it < 2; ++it) {
      int id = it * 256 + tid;
      int row = id >> 2, k8 = id & 3;
      bf16x8 v = *(const bf16x8*)(Bb + (size_t)row * K + kk + k8 * 8);
      *(bf16x8*)&Bs[row][k8 * 8] = v;
    }
    __syncthreads();

    // ---- MFMA: each wave 4x4 tiles of 16x16x32 ----
    bf16x8 af[4], bfr[4];
#pragma unroll
    for (int i = 0; i < 4; i++) af[i] = *(const bf16x8*)&As[wm + i * 16 + l16][quad * 8];
#pragma unroll
    for (int j = 0; j < 4; j++) bfr[j] = *(const bf16x8*)&Bs[wn + j * 16 + l16][quad * 8];
#pragma unroll
    for (int i = 0; i < 4; i++)
#pragma unroll
      for (int j = 0; j < 4; j++)
        acc[i][j] = __builtin_amdgcn_mfma_f32_16x16x32_bf16(af[i], bfr[j], acc[i][j], 0, 0, 0);
    __syncthreads();
  }

  // ---- epilogue: D row = quad*4+reg, col = lane&15 ----
#pragma unroll
  for (int i = 0; i < 4; i++) {
    int row0 = bm * BM + wm + i * 16 + quad * 4;
#pragma unroll
    for (int j = 0; j < 4; j++) {
      int col = bn * BN + wn + j * 16 + l16;
#pragma unroll
      for (int r = 0; r < 4; r++) {
        int row = row0 + r;
        size_t idx = (size_t)row * N + col;
        float v = acc[i][j][r];
        if constexpr (EPI == EPI_PLAIN) {
          C[idx] = (CT)v;
        } else if constexpr (EPI == EPI_GELU) {
          v += bias[col];
          float gl = 0.5f * v * (1.0f + erff(v * 0.70710678118654752f));
          C[idx] = (CT)gl;
        } else if constexpr (EPI == EPI_RES) {
          v += bias[col] + resid[idx];
          C[idx] = (CT)v;
        } else {  // EPI_GATE: sigmoid(v+b) * sigmoid(sup*wsg+bsg)
          v += bias[col];
          float g1 = 1.0f / (1.0f + expf(-v));
          float z = sup[row] * wsg[col] + bsg[col];
          float g2 = 1.0f / (1.0f + expf(-z));
          C[idx] = (CT)(g1 * g2);
        }
      }
    }
  }
}

// Chunked parallel scan: s_t = (1-g_t)*s_{t-1} + g_t*xt_t.
// Block: 512 threads = 32 channels x 16 chunks of 32 steps. Grid: (C/32, N).
// Phase 1: per-thread local scan (zero init), keep a_t and local prefix in regs.
// Phase 2: LDS carry combine (serial over 16 chunks, 32 threads).
// Phase 3: s_t = s_local_t + (prod a)_t * carry; write bf16 (only consumer is
//          G6, which converts A to bf16 during staging anyway).
constexpr int SC_CH = 32;   // steps per chunk
constexpr int SC_NCH = 16;  // chunks (T = 512)
constexpr int SC_CW = 32;   // channels per block

__global__ __launch_bounds__(512) void scan2_kernel(const float* __restrict__ g,
                                                    const float* __restrict__ xt,
                                                    bf16* __restrict__ s, int T, int C) {
  __shared__ float lA[SC_NCH][SC_CW];
  __shared__ float lB[SC_NCH][SC_CW];
  __shared__ float lC[SC_NCH][SC_CW];
  const int cl = threadIdx.x & (SC_CW - 1);
  const int ch = threadIdx.x / SC_CW;
  const int c = blockIdx.x * SC_CW + cl;
  const int n = blockIdx.y;
  const size_t base = ((size_t)n * T + ch * SC_CH) * C + c;

  float a_arr[SC_CH], sl[SC_CH];
  float A = 1.f, B = 0.f;
#pragma unroll
  for (int t = 0; t < SC_CH; ++t) {
    size_t idx = base + (size_t)t * C;
    float gv = g[idx], xv = xt[idx];
    float at = 1.0f - gv;
    a_arr[t] = at;
    B = at * B + gv * xv;
    sl[t] = B;
    A *= at;
  }
  lA[ch][cl] = A;
  lB[ch][cl] = B;
  __syncthreads();
  if (ch == 0) {
    float carry = 0.f;
#pragma unroll
    for (int j = 0; j < SC_NCH; ++j) {
      lC[j][cl] = carry;
      carry = lA[j][cl] * carry + lB[j][cl];
    }
  }
  __syncthreads();
  const float carry = lC[ch][cl];
  float P = 1.f;
#pragma unroll
  for (int t = 0; t < SC_CH; ++t) {
    P *= a_arr[t];
    s[base + (size_t)t * C] = (bf16)(sl[t] + P * carry);
  }
}

__global__ __launch_bounds__(256) void cvt_kernel(const float* __restrict__ in,
                                                  bf16* __restrict__ out, int n) {
  int i = blockIdx.x * 256 + threadIdx.x;
  if (i < n) out[i] = (bf16)in[i];
}

extern "C" void kernel_launch(void* const* d_in, const int* in_sizes, int n_in,
                              void* d_out, int out_size, void* d_ws, size_t ws_size,
                              hipStream_t stream) {
  const float* x_seq = (const float*)d_in[0];
  const float* sup = (const float*)d_in[1];
  const float* W_in = (const float*)d_in[2];
  const float* W_out = (const float*)d_in[3];
  const float* W_bg = (const float*)d_in[4];
  const float* b_bg = (const float*)d_in[5];
  const float* W_sg = (const float*)d_in[6];
  const float* b_sg = (const float*)d_in[7];
  const float* W_f1 = (const float*)d_in[8];
  const float* b_f1 = (const float*)d_in[9];
  const float* W_f2 = (const float*)d_in[10];
  const float* b_f2 = (const float*)d_in[11];

  const int Nb = 32, T = 512, C = 768, H = 1536;
  const int M = Nb * T;  // 16384

  char* ws = (char*)d_ws;
  size_t off = 0;
  auto alloc = [&](size_t bytes) {
    void* p = ws + off;
    off += (bytes + 255) & ~(size_t)255;
    return p;
  };
  bf16* Win_bf = (bf16*)alloc((size_t)C * C * 2);
  bf16* Wf1_bf = (bf16*)alloc((size_t)H * C * 2);
  bf16* Wf2_bf = (bf16*)alloc((size_t)C * H * 2);
  bf16* Wbg_bf = (bf16*)alloc((size_t)C * C * 2);
  bf16* Wout_bf = (bf16*)alloc((size_t)C * C * 2);
  float* x_f = (float*)alloc((size_t)M * C * 4);   // x; reused as s (bf16) after G4
  bf16* h_bf = (bf16*)alloc((size_t)M * H * 2);
  float* xt_f = (float*)alloc((size_t)M * C * 4);
  float* g_f = (float*)alloc((size_t)M * C * 4);
  bf16* s_bf = (bf16*)x_f;  // x dead after G3

  auto cvt = [&](const float* src, bf16* dst, int n) {
    cvt_kernel<<<(n + 255) / 256, 256, 0, stream>>>(src, dst, n);
  };
  cvt(W_in, Win_bf, C * C);
  cvt(W_f1, Wf1_bf, H * C);
  cvt(W_f2, Wf2_bf, C * H);
  cvt(W_bg, Wbg_bf, C * C);
  cvt(W_out, Wout_bf, C * C);

  dim3 blk(256);
  // G1: x = x_seq @ W_in^T
  gemm_bt<float, float, EPI_PLAIN><<<dim3(M / BM, C / BN), blk, 0, stream>>>(
      x_seq, Win_bf, x_f, nullptr, nullptr, nullptr, nullptr, nullptr, M, C, C);
  // G2: h = gelu(x @ W_f1^T + b_f1)  (bf16 out)
  gemm_bt<float, bf16, EPI_GELU><<<dim3(M / BM, H / BN), blk, 0, stream>>>(
      x_f, Wf1_bf, h_bf, b_f1, nullptr, nullptr, nullptr, nullptr, M, H, C);
  // G3: xt = x + h @ W_f2^T + b_f2
  gemm_bt<bf16, float, EPI_RES><<<dim3(M / BM, C / BN), blk, 0, stream>>>(
      h_bf, Wf2_bf, xt_f, b_f2, x_f, nullptr, nullptr, nullptr, M, C, H);
  // G4: g = sigmoid(xt @ W_bg^T + b_bg) * sigmoid(sup*W_sg + b_sg)
  gemm_bt<float, float, EPI_GATE><<<dim3(M / BM, C / BN), blk, 0, stream>>>(
      xt_f, Wbg_bf, g_f, b_bg, nullptr, sup, W_sg, b_sg, M, C, C);
  // scan: s_t = (1-g)*s_{t-1} + g*xt  (chunked parallel scan, bf16 out)
  scan2_kernel<<<dim3(C / SC_CW, Nb), dim3(SC_CW * SC_NCH), 0, stream>>>(
      g_f, xt_f, s_bf, T, C);
  // G6: out = s @ W_out^T  (bf16 A path)
  gemm_bt<bf16, float, EPI_PLAIN><<<dim3(M / BM, C / BN), blk, 0, stream>>>(
      s_bf, Wout_bf, (float*)d_out, nullptr, nullptr, nullptr, nullptr, nullptr, M, C, C);
}